// Round 4
// baseline (221.202 us; speedup 1.0000x reference)
//
#include <hip/hip_runtime.h>
#include <hip/hip_cooperative_groups.h>

namespace cg = cooperative_groups;

// Problem dims (from reference setup_inputs)
#define BB 4
#define CC 64
#define HH 256
#define WW 256
#define NPIX (HH*WW)          // 65536
#define NCLS 4
#define NPAIR 12              // B*(NCLS-1)
#define HALF 512
#define MAXS 1024
#define NOUT (NPAIR*CC*MAXS)  // 786432
#define CHUNK 4096
#define NCHUNK (NPIX/CHUNK)   // 16

// ---------------------------------------------------------------------------
// Single cooperative kernel: 256 blocks x 256 threads, 5 phases separated by
// grid.sync(). Phase code is identical to the (verified, absmax=0) round-3
// kernels; only the launch structure changed.
// ---------------------------------------------------------------------------
__global__ void __launch_bounds__(256) k_fused(
        const float* __restrict__ feat, const int* __restrict__ labels,
        const float* __restrict__ preds, float* __restrict__ out,
        unsigned char* __restrict__ pd, int* __restrict__ slots,
        int2* __restrict__ chunkBases, unsigned* __restrict__ chunkCounts,
        int* __restrict__ excessArr) {
    cg::grid_group grid = cg::this_grid();
    int bx = blockIdx.x, t = threadIdx.x;

    __shared__ unsigned char am[6][WW];   // phase 1
    __shared__ unsigned char vm[4][WW];   // phase 1
    __shared__ unsigned ws3[4][3];        // phase 2
    __shared__ unsigned ws4[4];           // phase 4

    // ---- Phase 1: fused argmax + separable 3x3 dilation (all 256 blocks) ----
    // block = one 4-row x 256-col band; lane x = t -> coalesced row loads.
    {
        int b = bx >> 6;
        int y0 = (bx & 63) * 4;
        int x = t;
        const float* pb = preds + (size_t)b * NCLS * NPIX;
#pragma unroll
        for (int r = 0; r < 6; ++r) {
            int y = y0 + r - 1;
            unsigned char a = 0;
            if (y >= 0 && y < HH) {
                const float* p = pb + y * WW + x;
                float best = p[0];
                int arg = 0;
#pragma unroll
                for (int c = 1; c < NCLS; ++c) {
                    float v = p[(size_t)c * NPIX];
                    if (v > best) { best = v; arg = c; }   // first-max wins (jnp.argmax)
                }
                a = (unsigned char)arg;
            }
            am[r][x] = a;
        }
        __syncthreads();
#pragma unroll
        for (int ry = 0; ry < 4; ++ry) {
            int m = am[ry][x];
            int v1 = am[ry + 1][x], v2 = am[ry + 2][x];
            if (v1 > m) m = v1;
            if (v2 > m) m = v2;
            vm[ry][x] = (unsigned char)m;
        }
        __syncthreads();
#pragma unroll
        for (int ry = 0; ry < 4; ++ry) {
            int m = vm[ry][x];
            if (x > 0)      { int v = vm[ry][x - 1]; if (v > m) m = v; }
            if (x < WW - 1) { int v = vm[ry][x + 1]; if (v > m) m = v; }
            pd[b * NPIX + (y0 + ry) * WW + x] = (unsigned char)m;
        }
    }
    grid.sync();

    // ---- Phase 2: per-(image,chunk) hard/easy counts for all 3 classes
    //      (blocks 0..63) + slot-table init to -1 (blocks 0..47) ----
    if (bx < 48) slots[bx * 256 + t] = -1;
    if (bx < 64) {
        int chunk = bx & 15, b = bx >> 4;
        const int4*   lab4 = (const int4*)(labels + b * NPIX);
        const uchar4* pd4  = (const uchar4*)(pd + b * NPIX);
        unsigned pk[3] = {0u, 0u, 0u};
#pragma unroll
        for (int j = 0; j < 4; ++j) {
            int idx = chunk * (CHUNK / 4) + j * 256 + t;   // coalesced 16B/lane
            int4 lv = lab4[idx];
            uchar4 dv = pd4[idx];
            int ls[4] = {lv.x, lv.y, lv.z, lv.w};
            int ds[4] = {dv.x, dv.y, dv.z, dv.w};
#pragma unroll
            for (int e = 0; e < 4; ++e)
#pragma unroll
                for (int c = 0; c < 3; ++c)
                    if (ls[e] == c + 1) pk[c] += (ds[e] == c + 1) ? (1u << 16) : 1u;
        }
        int lane = t & 63, w = t >> 6;
#pragma unroll
        for (int c = 0; c < 3; ++c)
#pragma unroll
            for (int off = 32; off > 0; off >>= 1)
                pk[c] += (unsigned)__shfl_down((int)pk[c], off, 64);
        if (lane == 0) { ws3[w][0] = pk[0]; ws3[w][1] = pk[1]; ws3[w][2] = pk[2]; }
        __syncthreads();
        if (t < 3)
            chunkCounts[(b * 3 + t) * NCHUNK + chunk] =
                ws3[0][t] + ws3[1][t] + ws3[2][t] + ws3[3][t];
    }
    grid.sync();

    // ---- Phase 3: tiny per-pair scan of chunk counts (block 0) ----
    if (bx == 0 && t < NPAIR) {
        int hb = 0, eb = 0;
        for (int ch = 0; ch < NCHUNK; ++ch) {
            unsigned v = chunkCounts[t * NCHUNK + ch];
            chunkBases[t * NCHUNK + ch] = make_int2(hb, eb);
            hb += (int)(v & 0xffffu);
            eb += (int)(v >> 16);
        }
        int ex = hb - HALF;
        excessArr[t] = ex > 0 ? ex : 0;
        out[NOUT + t] = (float)(t % 3 + 1);   // feat_label
    }
    grid.sync();

    // ---- Phase 4: slot assignment (blocks 0..191; pair = bx/16, chunk = bx%16)
    //  hard rank r  -> slot r                 (if r < 1024)
    //  easy rank e  -> slot 512 + excess + e  (if < 1024)
    if (bx < NPAIR * NCHUNK) {
        int pair = bx >> 4, chunk = bx & 15;
        int b = pair / 3, cls = pair % 3 + 1;
        int2 base = chunkBases[pair * NCHUNK + chunk];
        int excess = excessArr[pair];
        if (!(base.x >= MAXS && HALF + excess + base.y >= MAXS)) {   // block-uniform skip
            const int4* lab4 = (const int4*)(labels + b * NPIX + chunk * CHUNK + t * 16);
            const uint4* pd16 = (const uint4*)(pd + b * NPIX + chunk * CHUNK + t * 16);
            int4 l0 = lab4[0], l1 = lab4[1], l2 = lab4[2], l3 = lab4[3];
            uint4 dp = pd16[0];
            int ls[16] = {l0.x, l0.y, l0.z, l0.w, l1.x, l1.y, l1.z, l1.w,
                          l2.x, l2.y, l2.z, l2.w, l3.x, l3.y, l3.z, l3.w};
            unsigned char ds[16];
            unsigned dw[4] = {dp.x, dp.y, dp.z, dp.w};
#pragma unroll
            for (int j = 0; j < 16; ++j) ds[j] = (dw[j >> 2] >> ((j & 3) * 8)) & 0xff;

            unsigned mine = 0;
#pragma unroll
            for (int j = 0; j < 16; ++j)
                if (ls[j] == cls) mine += (ds[j] == cls) ? (1u << 16) : 1u;

            int lane = t & 63, w = t >> 6;
            unsigned v = mine;
#pragma unroll
            for (int off = 1; off < 64; off <<= 1) {
                unsigned u = (unsigned)__shfl_up((int)v, off, 64);
                if (lane >= off) v += u;
            }
            if (lane == 63) ws4[w] = v;
            __syncthreads();
            unsigned waveBase = 0;
            for (int i = 0; i < w; ++i) waveBase += ws4[i];
            unsigned excl = waveBase + v - mine;

            int hr = base.x + (int)(excl & 0xffffu);
            int er = base.y + (int)(excl >> 16);
            int pixBase = chunk * CHUNK + t * 16;
            int* sl = slots + pair * MAXS;
#pragma unroll
            for (int j = 0; j < 16; ++j) {
                if (ls[j] == cls) {
                    if (ds[j] != cls) {
                        if (hr < MAXS) sl[hr] = pixBase + j;
                        hr++;
                    } else {
                        int pos = HALF + excess + er;
                        if (pos < MAXS) sl[pos] = pixBase + j;
                        er++;
                    }
                }
            }
        }
    }
    grid.sync();

    // ---- Phase 5: gather, 3 float4 quads per thread (all blocks) ----
    {
        int i0 = bx * 256 + t;
#pragma unroll
        for (int k = 0; k < 3; ++k) {
            int i = i0 + k * 65536;              // NQ = 196608 = 3 * 65536
            int q = i << 2;
            int pair = q >> 16;                  // CC*MAXS = 65536
            int c = (q >> 10) & (CC - 1);
            int slot = q & (MAXS - 1);
            int b = pair / 3;
            const float* fp = feat + ((size_t)(b * CC + c)) * NPIX;
            const int* sp = slots + pair * MAXS + slot;
            int p0 = sp[0], p1 = sp[1], p2 = sp[2], p3 = sp[3];
            float4 o;
            o.x = (p0 >= 0) ? fp[p0] : 0.0f;
            o.y = (p1 >= 0) ? fp[p1] : 0.0f;
            o.z = (p2 >= 0) ? fp[p2] : 0.0f;
            o.w = (p3 >= 0) ? fp[p3] : 0.0f;
            ((float4*)out)[i] = o;
        }
    }
}

extern "C" void kernel_launch(void* const* d_in, const int* in_sizes, int n_in,
                              void* d_out, int out_size, void* d_ws, size_t ws_size,
                              hipStream_t stream) {
    const float* feat   = (const float*)d_in[0];  // [B,C,H,W] fp32
    const int*   labels = (const int*)d_in[1];    // [B,H,W] int32
    const float* preds  = (const float*)d_in[2];  // [B,NCLS,H,W] fp32
    float* out = (float*)d_out;

    // workspace layout (all offsets 16B-aligned)
    unsigned char* pd = (unsigned char*)d_ws;                          // 262144 B
    int* slots = (int*)(pd + BB * NPIX);                               // 12288 ints
    int2* chunkBases = (int2*)(slots + NPAIR * MAXS);                  // 192 int2
    unsigned* chunkCounts = (unsigned*)(chunkBases + NPAIR * NCHUNK);  // 192 uint
    int* excessArr = (int*)(chunkCounts + NPAIR * NCHUNK);             // 12 ints

    void* args[] = {(void*)&feat, (void*)&labels, (void*)&preds, (void*)&out,
                    (void*)&pd, (void*)&slots, (void*)&chunkBases,
                    (void*)&chunkCounts, (void*)&excessArr};
    hipLaunchCooperativeKernel((void*)k_fused, dim3(256), dim3(256), args, 0, stream);
}

// Round 5
// 106.494 us; speedup vs baseline: 2.0771x; 2.0771x over previous
//
#include <hip/hip_runtime.h>

// Problem dims (from reference setup_inputs)
#define BB 4
#define CC 64
#define HH 256
#define WW 256
#define NPIX (HH*WW)          // 65536
#define NCLS 4
#define NPAIR 12              // B*(NCLS-1)
#define HALF 512
#define MAXS 1024
#define NOUT (NPAIR*CC*MAXS)  // 786432
#define CHUNK 4096
#define NCHUNK (NPIX/CHUNK)   // 16
#define NBAND 64              // 4-row bands per image
#define BANDPIX (NPIX/NBAND)  // 1024

// ---------------------------------------------------------------------------
// K1: fused argmax + separable 3x3 dilation + per-band hard/easy counting.
// Block = one 4-row x 256-col band (256 blocks total). Lane x = threadIdx.x:
// all preds/labels loads are coalesced rows. Vertical 3-max is per-column
// (registers); only the horizontal 3-max needs the LDS row exchange.
// Counts are packed hard | easy<<16 per class, written once per (pair,band)
// -> no atomics, no zero-init. OOB halo rows use argmax=0 (safe: the window
// always contains the center pixel, class >= 0).
// ---------------------------------------------------------------------------
__global__ void __launch_bounds__(256) k_dargmax(
        const float* __restrict__ preds, const int* __restrict__ labels,
        unsigned char* __restrict__ pd, unsigned* __restrict__ bandCounts) {
    __shared__ unsigned char vm[4][WW];
    __shared__ unsigned wsum[4][3];
    int bx = blockIdx.x;
    int b = bx >> 6, band = bx & 63;
    int y0 = band * 4;
    int x = threadIdx.x;
    const float* pb = preds + (size_t)b * NCLS * NPIX;

    unsigned char am[6];
#pragma unroll
    for (int r = 0; r < 6; ++r) {
        int y = y0 + r - 1;
        unsigned char a = 0;
        if (y >= 0 && y < HH) {
            const float* p = pb + y * WW + x;
            float best = p[0];
            int arg = 0;
#pragma unroll
            for (int c = 1; c < NCLS; ++c) {
                float v = p[(size_t)c * NPIX];
                if (v > best) { best = v; arg = c; }   // first-max wins (jnp.argmax)
            }
            a = (unsigned char)arg;
        }
        am[r] = a;
    }
    unsigned char vmr[4];
#pragma unroll
    for (int ry = 0; ry < 4; ++ry) {
        int m = am[ry];
        if (am[ry + 1] > m) m = am[ry + 1];
        if (am[ry + 2] > m) m = am[ry + 2];
        vmr[ry] = (unsigned char)m;
        vm[ry][x] = (unsigned char)m;
    }
    __syncthreads();

    unsigned pk[3] = {0u, 0u, 0u};
#pragma unroll
    for (int ry = 0; ry < 4; ++ry) {
        int m = vmr[ry];
        if (x > 0)      { int v = vm[ry][x - 1]; if (v > m) m = v; }
        if (x < WW - 1) { int v = vm[ry][x + 1]; if (v > m) m = v; }
        int idx = b * NPIX + (y0 + ry) * WW + x;
        pd[idx] = (unsigned char)m;
        int l = labels[idx];
#pragma unroll
        for (int c = 0; c < 3; ++c)
            if (l == c + 1) pk[c] += (m == c + 1) ? (1u << 16) : 1u;
    }
    // block reduce the 3 packed counters (fields can't overflow: <= 1024/band)
    int lane = x & 63, w = x >> 6;
#pragma unroll
    for (int c = 0; c < 3; ++c)
#pragma unroll
        for (int off = 32; off > 0; off >>= 1)
            pk[c] += (unsigned)__shfl_down((int)pk[c], off, 64);
    if (lane == 0) { wsum[w][0] = pk[0]; wsum[w][1] = pk[1]; wsum[w][2] = pk[2]; }
    __syncthreads();
    if (x < 3)
        bandCounts[(b * 3 + x) * NBAND + band] =
            wsum[0][x] + wsum[1][x] + wsum[2][x] + wsum[3][x];
}

// ---------------------------------------------------------------------------
// K2: slot assignment. Grid (chunk,pair) flattened = 192 blocks, 256 threads,
// 16 contiguous px/thread in registers. Each block redundantly prefix-sums its
// pair's 64 band counts (LDS) to get the chunk's base ranks + the pair total
// (for excess) -- this absorbs the old k_scan kernel. Chunk-0 block also
// writes pairTotals and the feat_label outputs.
//  hard rank r  -> slot r                 (if r < 1024)
//  easy rank e  -> slot 512 + excess + e  (if < 1024)
// ---------------------------------------------------------------------------
__global__ void __launch_bounds__(256) k_assign(
        const int* __restrict__ labels, const unsigned char* __restrict__ pd,
        const unsigned* __restrict__ bandCounts, unsigned* __restrict__ pairTotals,
        int* __restrict__ slots, float* __restrict__ out) {
    int pair = blockIdx.x >> 4, chunk = blockIdx.x & 15;
    int b = pair / 3, cls = pair % 3 + 1;
    int t = threadIdx.x;
    __shared__ unsigned bc[NBAND];
    __shared__ unsigned ws[4];
    if (t < NBAND) bc[t] = bandCounts[pair * NBAND + t];
    __syncthreads();
    // redundant per-thread: prefix up to band chunk*4, and full total
    unsigned base = 0, total = 0;
    int cut = chunk * 4;
#pragma unroll
    for (int i = 0; i < NBAND; ++i) {
        unsigned v = bc[i];
        total += v;
        if (i < cut) base += v;
    }
    if (chunk == 0 && t == 0) {
        pairTotals[pair] = total;
        out[NOUT + pair] = (float)cls;        // feat_label
    }
    int excess = (int)(total & 0xffffu) - HALF;
    if (excess < 0) excess = 0;
    int baseH = (int)(base & 0xffffu), baseE = (int)(base >> 16);
    if (baseH >= MAXS && HALF + excess + baseE >= MAXS) return;   // nothing lands

    const int4* lab4 = (const int4*)(labels + b * NPIX + chunk * CHUNK + t * 16);
    const uint4* pd16 = (const uint4*)(pd + b * NPIX + chunk * CHUNK + t * 16);
    int4 l0 = lab4[0], l1 = lab4[1], l2 = lab4[2], l3 = lab4[3];
    uint4 dp = pd16[0];
    int ls[16] = {l0.x, l0.y, l0.z, l0.w, l1.x, l1.y, l1.z, l1.w,
                  l2.x, l2.y, l2.z, l2.w, l3.x, l3.y, l3.z, l3.w};
    unsigned char ds[16];
    unsigned dw[4] = {dp.x, dp.y, dp.z, dp.w};
#pragma unroll
    for (int j = 0; j < 16; ++j) ds[j] = (dw[j >> 2] >> ((j & 3) * 8)) & 0xff;

    unsigned mine = 0;
#pragma unroll
    for (int j = 0; j < 16; ++j)
        if (ls[j] == cls) mine += (ds[j] == cls) ? (1u << 16) : 1u;

    int lane = t & 63, w = t >> 6;
    unsigned v = mine;
#pragma unroll
    for (int off = 1; off < 64; off <<= 1) {
        unsigned u = (unsigned)__shfl_up((int)v, off, 64);
        if (lane >= off) v += u;
    }
    if (lane == 63) ws[w] = v;
    __syncthreads();
    unsigned waveBase = 0;
    for (int i = 0; i < w; ++i) waveBase += ws[i];
    unsigned excl = waveBase + v - mine;

    int hr = baseH + (int)(excl & 0xffffu);
    int er = baseE + (int)(excl >> 16);
    int pixBase = chunk * CHUNK + t * 16;
    int* sl = slots + pair * MAXS;
#pragma unroll
    for (int j = 0; j < 16; ++j) {
        if (ls[j] == cls) {
            if (ds[j] != cls) {
                if (hr < MAXS) sl[hr] = pixBase + j;
                hr++;
            } else {
                int pos = HALF + excess + er;
                if (pos < MAXS) sl[pos] = pixBase + j;
                er++;
            }
        }
    }
}

// ---------------------------------------------------------------------------
// K3: gather. Validity is computed arithmetically from pairTotals (the exact
// fill intervals of k_assign), so slots[] needs no -1 init; the slots read is
// predicated on validity (poisoned entries never dereferenced).
// 4 consecutive slots per thread, float4 store; pair (hence pairTotals) is
// uniform across each block -> scalar load.
// ---------------------------------------------------------------------------
__global__ void __launch_bounds__(256) k_gather(
        const float* __restrict__ feat, const int* __restrict__ slots,
        const unsigned* __restrict__ pairTotals, float* __restrict__ out) {
    int i = blockIdx.x * 256 + threadIdx.x;      // < NOUT/4 = 196608
    int q = i << 2;
    int pair = q >> 16;                          // CC*MAXS = 65536
    unsigned tot = pairTotals[pair];
    int Nh = (int)(tot & 0xffffu), Ne = (int)(tot >> 16);
    int excess = Nh - HALF; if (excess < 0) excess = 0;
    int hardEnd = Nh < MAXS ? Nh : MAXS;
    int easyStart = HALF + excess;
    int easyEnd = easyStart + Ne; if (easyEnd > MAXS) easyEnd = MAXS;

    int c = (q >> 10) & (CC - 1);
    int slot = q & (MAXS - 1);
    int b = pair / 3;
    const float* fp = feat + ((size_t)(b * CC + c)) * NPIX;
    const int* sp = slots + pair * MAXS + slot;
    float o[4];
#pragma unroll
    for (int j = 0; j < 4; ++j) {
        int s = slot + j;
        bool valid = (s < hardEnd) || (s >= easyStart && s < easyEnd);
        float val = 0.0f;
        if (valid) val = fp[sp[j]];
        o[j] = val;
    }
    ((float4*)out)[i] = make_float4(o[0], o[1], o[2], o[3]);
}

extern "C" void kernel_launch(void* const* d_in, const int* in_sizes, int n_in,
                              void* d_out, int out_size, void* d_ws, size_t ws_size,
                              hipStream_t stream) {
    const float* feat   = (const float*)d_in[0];  // [B,C,H,W] fp32
    const int*   labels = (const int*)d_in[1];    // [B,H,W] int32
    const float* preds  = (const float*)d_in[2];  // [B,NCLS,H,W] fp32
    float* out = (float*)d_out;

    // workspace layout (all offsets 16B-aligned)
    unsigned char* pd = (unsigned char*)d_ws;                    // 262144 B
    int* slots = (int*)(pd + BB * NPIX);                         // 12288 ints
    unsigned* bandCounts = (unsigned*)(slots + NPAIR * MAXS);    // 768 uints
    unsigned* pairTotals = bandCounts + NPAIR * NBAND;           // 12 uints

    k_dargmax<<<NBAND * BB, 256, 0, stream>>>(preds, labels, pd, bandCounts);
    k_assign<<<NPAIR * NCHUNK, 256, 0, stream>>>(labels, pd, bandCounts, pairTotals, slots, out);
    k_gather<<<NOUT / 4 / 256, 256, 0, stream>>>(feat, slots, pairTotals, out);
}